// Round 7
// baseline (58.107 us; speedup 1.0000x reference)
//
#include <hip/hip_runtime.h>
#include <math.h>

#ifndef M_PI
#define M_PI 3.14159265358979323846
#endif

#define NWIN   400
#define NSHIFT 160
#define NMELS  80
#define NFRM   998
#define WLEN   160000
#define FPB    4
#define BPB    250          // frame-blocks per batch (249 full + 1 tail of 2)
#define EPSV   1.1920929e-07f
#define WROW   40           // bf16 weights per mel row (aligned chunk coverage)

// workspace layout (float units)
#define WIN_OFF  0      // [400]   Povey window
#define TWID_OFF 400    // [85*6]  per-stage radix-4 twiddles
#define WEXP_OFF 912    // [128*2] untangle W[k]=e^{-i pi k/256} (cos,-sin)
#define MELB_OFF 1168   // [80] int2 (base, nchunks)
#define MELW_OFF 1328   // [80*40 ushort = 1600 floats] bf16 mel weights
#define WS_FLOATS 2928  // 11712 B

// XOR swizzle on complex (float2) slot index: all 4 FFT stages hit the
// 4-lane-per-bank-pair floor for b64.
__device__ __forceinline__ int swz(int s) { return s ^ ((s >> 4) & 15); }

__device__ __forceinline__ ushort f2bf(float v) {   // RNE float->bf16
    unsigned b = __float_as_uint(v);
    return (ushort)((b + 0x7FFFu + ((b >> 16) & 1u)) >> 16);
}

__global__ __launch_bounds__(128)
void setup_kernel(float* __restrict__ ws)
{
    const int gid = blockIdx.x * 128 + threadIdx.x;   // grid 8 x 128
    const double ML = 1127.0 * log(1.0 + 20.0 / 700.0);
    const double MH = 1127.0 * log(1.0 + 8000.0 / 700.0);
    const double DD = (MH - ML) / (double)(NMELS + 1);

    if (gid < NWIN) {
        double a = 0.5 - 0.5 * cos(2.0 * M_PI * (double)gid / 399.0);
        if (a < 0.0) a = 0.0;
        ws[WIN_OFF + gid] = (float)pow(a, 0.85);
    } else if (gid >= 400 && gid < 485) {
        int e = gid - 400, st, j;
        if      (e < 64) { st = 0; j = e; }
        else if (e < 80) { st = 1; j = e - 64; }
        else if (e < 84) { st = 2; j = e - 80; }
        else             { st = 3; j = 0; }
        int Q = 64 >> (2 * st);
        double ang = -M_PI * (double)j / (2.0 * (double)Q);   // -2*pi*j/(4Q)
        float* t = ws + TWID_OFF + e * 6;
        t[0] = (float)cos(ang);       t[1] = (float)sin(ang);
        t[2] = (float)cos(2.0 * ang); t[3] = (float)sin(2.0 * ang);
        t[4] = (float)cos(3.0 * ang); t[5] = (float)sin(3.0 * ang);
    } else if (gid >= 512 && gid < 640) {
        int k = gid - 512;
        double th = M_PI * (double)k / 256.0;
        ws[WEXP_OFF + 2 * k]     = (float)cos(th);
        ws[WEXP_OFF + 2 * k + 1] = (float)(-sin(th));
    } else if (gid >= 640 && gid < 640 + NMELS) {
        int j = gid - 640;
        double mlo = ML + (double)j * DD;
        double mhi = mlo + 2.0 * DD;
        double flo = 700.0 * (exp(mlo / 1127.0) - 1.0);
        double fhi = 700.0 * (exp(mhi / 1127.0) - 1.0);
        int blo = max(1,   (int)(flo / 31.25));        // +-1 slack: weights clamp to 0
        int bhi = min(255, (int)(fhi / 31.25) + 1);
        int base = blo & ~7;
        int nc   = (bhi - base + 8) >> 3;              // ceil((bhi-base+1)/8) <= 4
        ((int2*)(ws + MELB_OFF))[j] = make_int2(base, nc);
        ushort* wrow = (ushort*)(ws + MELW_OFF) + j * WROW;
        for (int i = 0; i < WROW; ++i) {
            int b = base + i;
            double u = (1127.0 * log(1.0 + (double)b * 31.25 / 700.0) - ML) / DD;
            double w = fmax(0.0, fmin(u - (double)j, (double)(j + 2) - u));
            wrow[i] = f2bf((float)w);                  // 0 outside [blo,bhi]
        }
    }
}

template<bool USE_TAB>
__global__ __launch_bounds__(256)
void fbank_kernel(const float* __restrict__ wav, float* __restrict__ out,
                  const float* __restrict__ ws)
{
    __shared__ __align__(16) float  zbf[FPB][512];      // per-wave complex buffer (8192B)
    __shared__ __align__(16) float  pbuf[FPB][288];     // power spectrum + zero pad (4608B)
    __shared__ __align__(16) ushort wtab[NMELS * WROW]; // bf16 mel weights (6400B)
    __shared__ __align__(16) float  res[NMELS * FPB];   // logmel [mel][slot] (1280B)
    // total LDS = 20480 B -> 8 blocks/CU (full 32-wave occupancy)

    const int tid  = threadIdx.x;
    const int lane = tid & 63;
    const int wv   = tid >> 6;                 // one wave per frame
    const int bb   = blockIdx.x / BPB;
    const int f0   = (blockIdx.x % BPB) * FPB;
    const bool valid = (f0 + wv) < NFRM;

    const float MLf = 1127.0f * __logf(1.0f + 20.0f / 700.0f);
    const float MHf = 1127.0f * __logf(1.0f + 8000.0f / 700.0f);
    const float DDf = (MHf - MLf) / (float)(NMELS + 1);

    // ---- stage bf16 weight table (1600 dwords) ----
    if constexpr (USE_TAB) {
        const unsigned* src = (const unsigned*)(ws + MELW_OFF);
        unsigned* dst = (unsigned*)wtab;
        #pragma unroll
        for (int i = 0; i < 7; ++i) {
            int o = tid + 256 * i;
            if (o < NMELS * WROW / 2) dst[o] = src[o];
        }
    } else {
        if (tid < NMELS) {
            int j = tid;
            float mlo = MLf + (float)j * DDf;
            float mhi = mlo + 2.0f * DDf;
            float flo = 700.0f * (__expf(mlo * (1.0f / 1127.0f)) - 1.0f);
            float fhi = 700.0f * (__expf(mhi * (1.0f / 1127.0f)) - 1.0f);
            int blo = max(1,   (int)(flo * (1.0f / 31.25f)));
            int bhi = min(255, (int)(fhi * (1.0f / 31.25f)) + 1);
            int base = blo & ~7;
            for (int i = 0; i < WROW; ++i) {
                int b = base + i;
                float u = (1127.0f * __logf(1.0f + (float)b * (31.25f / 700.0f)) - MLf) / DDf;
                wtab[j * WROW + i] = f2bf(fmaxf(0.0f, fminf(u - (float)j, (float)(j + 2) - u)));
            }
        }
    }
    // zero the pbuf pad (bins 256..287) so aligned over-reads hit exact zeros
    if (lane < 32) pbuf[wv][256 + lane] = 0.0f;
    __syncthreads();

    float*  zf = zbf[wv];
    float2* zc = (float2*)zf;

    // ---- preprocess: de-mean, pre-emphasis (2nd load), window; pack pairs ----
    if (valid) {
        const float* xp = wav + (size_t)bb * WLEN + (size_t)(f0 + wv) * NSHIFT;
        float xc[7], xm[7], wn[7];
        float s = 0.0f;
        #pragma unroll
        for (int t = 0; t < 7; ++t) {
            int n = 64 * t + lane;
            bool vn = (t < 6 || lane < 16);
            xc[t] = vn ? xp[n] : 0.0f;
            xm[t] = (vn && n > 0) ? xp[n - 1] : 0.0f;   // L1-hit reload
            if constexpr (USE_TAB) {
                wn[t] = vn ? ws[WIN_OFF + n] : 0.0f;    // L1-resident window
            } else {
                float a = fmaxf(0.5f - 0.5f * __cosf((float)n * (float)(2.0 * M_PI / 399.0)), 0.0f);
                wn[t] = __powf(a, 0.85f);
            }
            s += xc[t];
        }
        if (lane == 0) xm[0] = xc[0];                   // ref: prev[0] = x[0]
        #pragma unroll
        for (int off = 32; off > 0; off >>= 1) s += __shfl_xor(s, off, 64);
        const float mu3 = 0.03f * (s * (1.0f / (float)NWIN));
        #pragma unroll
        for (int t = 0; t < 7; ++t) {
            int n = 64 * t + lane;
            float y = 0.0f;
            if (t < 6 || lane < 16)
                y = (fmaf(-0.97f, xm[t], xc[t]) - mu3) * wn[t];
            zf[(swz(n >> 1) << 1) | (n & 1)] = y;       // n>=400 slots get 0
        }
        zf[(swz((448 + lane) >> 1) << 1) | (lane & 1)] = 0.0f;  // pad z[224..255]
    }

    // ---- 256-point radix-4 DIF FFT, in-place, digit-reversed output ----
    // Wave-private LDS: same-wave DS ordering + compiler lgkmcnt suffice.
    if (valid) {
        #pragma unroll
        for (int st = 0; st < 4; ++st) {
            const int Q = 64 >> (2 * st);                 // L/4
            int j  = lane & (Q - 1);
            int i0 = ((lane & ~(Q - 1)) << 2) + j;        // base + j
            float2 a0 = zc[swz(i0)];
            float2 a1 = zc[swz(i0 + Q)];
            float2 a2 = zc[swz(i0 + 2 * Q)];
            float2 a3 = zc[swz(i0 + 3 * Q)];
            float t0x = a0.x + a2.x, t0y = a0.y + a2.y;
            float t1x = a1.x + a3.x, t1y = a1.y + a3.y;
            float t2x = a0.x - a2.x, t2y = a0.y - a2.y;
            float t3x = a1.x - a3.x, t3y = a1.y - a3.y;
            float b0x = t0x + t1x, b0y = t0y + t1y;       // q=0
            float b2x = t0x - t1x, b2y = t0y - t1y;       // q=2
            float b1x = t2x + t3y, b1y = t2y - t3x;       // q=1: t2 - i*t3
            float b3x = t2x - t3y, b3y = t2y + t3x;       // q=3: t2 + i*t3
            float cn, sn, w2x, w2y, w3x, w3y;
            if constexpr (USE_TAB) {
                constexpr int TOFF[4] = {0, 64, 80, 84};
                const float* tw = ws + TWID_OFF + (TOFF[st] + j) * 6;
                cn = tw[0]; sn = tw[1]; w2x = tw[2]; w2y = tw[3]; w3x = tw[4]; w3y = tw[5];
            } else {
                float ang = (float)j * (float)(-M_PI / 2.0 / (double)Q);
                __sincosf(ang, &sn, &cn);
                w2x = cn * cn - sn * sn; w2y = 2.0f * cn * sn;
                w3x = w2x * cn - w2y * sn; w3y = w2x * sn + w2y * cn;
            }
            zc[swz(i0)]       = make_float2(b0x, b0y);
            zc[swz(i0 + Q)]   = make_float2(fmaf(b1x, cn,  -b1y * sn),  fmaf(b1x, sn,  b1y * cn));
            zc[swz(i0 + 2*Q)] = make_float2(fmaf(b2x, w2x, -b2y * w2y), fmaf(b2x, w2y, b2y * w2x));
            zc[swz(i0 + 3*Q)] = make_float2(fmaf(b3x, w3x, -b3y * w3y), fmaf(b3x, w3y, b3y * w3x));
        }
    }

    // ---- pair-symmetric untangle + power ----
    // X[k] = E + W*O, X[256-k] = conj(E - W*O); p = |X|^2.
    if (valid) {
        const int rl = ((lane & 3) << 6) | (((lane >> 2) & 3) << 4) | (((lane >> 4) & 3) << 2);
        #pragma unroll
        for (int r = 0; r < 2; ++r) {
            int k  = 64 * r + lane;
            int m8 = (256 - k) & 255;
            int rk = rl | r;
            int rm = ((m8 & 3) << 6) | (((m8 >> 2) & 3) << 4) | (((m8 >> 4) & 3) << 2) | ((m8 >> 6) & 3);
            float2 Zk = zc[swz(rk)];
            float2 Zm = zc[swz(rm)];
            float Sx = Zk.x + Zm.x, Sy = Zk.y - Zm.y;   // 2E
            float Ox = Zk.y + Zm.y, Oy = Zm.x - Zk.x;   // 2O
            float Wx, Wy;
            if constexpr (USE_TAB) {
                float2 w = ((const float2*)(ws + WEXP_OFF))[k];
                Wx = w.x; Wy = w.y;
            } else {
                __sincosf((float)k * (float)(-M_PI / 256.0), &Wy, &Wx);
            }
            float Ux = fmaf(Wx, Ox, -Wy * Oy), Uy = fmaf(Wx, Oy, Wy * Ox);  // 2*W*O
            float q1 = Sx + Ux, q2 = Sy + Uy;
            float q3 = Sx - Ux, q4 = Sy - Uy;
            pbuf[wv][k] = 0.25f * fmaf(q1, q1, q2 * q2);
            if (m8 != 0)                                  // m8==0 <=> bin 256 (weight 0)
                pbuf[wv][m8] = 0.25f * fmaf(q3, q3, q4 * q4);
        }
        if (lane == 0) {   // bin 128 self-paired: |X|^2 = |Z[128]|^2, rev4(128)=2
            float2 Z = zc[swz(2)];
            pbuf[wv][128] = fmaf(Z.x, Z.x, Z.y * Z.y);
        }
    }

    // ---- mel gather: vectorized 16B chunks, bf16 weights ----
    if (valid) {
        #pragma unroll
        for (int half = 0; half < 2; ++half) {
            int j = half * 64 + lane;
            if (j < NMELS) {
                int base, nc;
                if constexpr (USE_TAB) {
                    int2 mb = ((const int2*)(ws + MELB_OFF))[j];
                    base = mb.x; nc = mb.y;
                } else {
                    float mlo = MLf + (float)j * DDf;
                    float mhi = mlo + 2.0f * DDf;
                    float flo = 700.0f * (__expf(mlo * (1.0f / 1127.0f)) - 1.0f);
                    float fhi = 700.0f * (__expf(mhi * (1.0f / 1127.0f)) - 1.0f);
                    int blo = max(1,   (int)(flo * (1.0f / 31.25f)));
                    int bhi = min(255, (int)(fhi * (1.0f / 31.25f)) + 1);
                    base = blo & ~7;
                    nc   = (bhi - base + 8) >> 3;
                }
                float acc = 0.0f;
                for (int c = 0; c < nc; ++c) {
                    float4 p0 = *(const float4*)&pbuf[wv][base + 8 * c];
                    float4 p1 = *(const float4*)&pbuf[wv][base + 8 * c + 4];
                    uint4  wb = *(const uint4*)&wtab[j * WROW + 8 * c];
                    acc = fmaf(__uint_as_float(wb.x << 16),          p0.x, acc);
                    acc = fmaf(__uint_as_float(wb.x & 0xffff0000u),  p0.y, acc);
                    acc = fmaf(__uint_as_float(wb.y << 16),          p0.z, acc);
                    acc = fmaf(__uint_as_float(wb.y & 0xffff0000u),  p0.w, acc);
                    acc = fmaf(__uint_as_float(wb.z << 16),          p1.x, acc);
                    acc = fmaf(__uint_as_float(wb.z & 0xffff0000u),  p1.y, acc);
                    acc = fmaf(__uint_as_float(wb.w << 16),          p1.z, acc);
                    acc = fmaf(__uint_as_float(wb.w & 0xffff0000u),  p1.w, acc);
                }
                res[j * FPB + wv] = __logf(fmaxf(acc, EPSV));
            }
        }
    }
    __syncthreads();

    // ---- transposed output, 8B bursts ----
    const int nval = min(FPB, NFRM - f0);
    if (tid < NMELS) {
        size_t o = ((size_t)bb * NMELS + tid) * NFRM + (size_t)f0;
        *(float2*)&out[o] = make_float2(res[tid * 4 + 0], res[tid * 4 + 1]);
        if (nval == 4)
            *(float2*)&out[o + 2] = make_float2(res[tid * 4 + 2], res[tid * 4 + 3]);
    }
}

extern "C" void kernel_launch(void* const* d_in, const int* in_sizes, int n_in,
                              void* d_out, int out_size, void* d_ws, size_t ws_size,
                              hipStream_t stream)
{
    const float* wav = (const float*)d_in[0];
    float* out = (float*)d_out;
    float* ws  = (float*)d_ws;
    if (ws != nullptr && ws_size >= WS_FLOATS * sizeof(float)) {
        setup_kernel<<<dim3(8), dim3(128), 0, stream>>>(ws);
        fbank_kernel<true><<<dim3(32 * BPB), dim3(256), 0, stream>>>(wav, out, ws);
    } else {
        fbank_kernel<false><<<dim3(32 * BPB), dim3(256), 0, stream>>>(wav, out, ws);
    }
}

// Round 8
// 55.701 us; speedup vs baseline: 1.0432x; 1.0432x over previous
//
#include <hip/hip_runtime.h>
#include <math.h>

#ifndef M_PI
#define M_PI 3.14159265358979323846
#endif

#define NWIN   400
#define NSHIFT 160
#define NMELS  80
#define NFRM   998
#define WLEN   160000
#define FPB    4
#define BPB    250          // frame-blocks per batch (249 full + 1 tail of 2)
#define EPSV   1.1920929e-07f

// workspace layout (float units)
#define WIN_OFF  0      // [400]   Povey window
#define TWID_OFF 400    // [85*6]  per-stage radix-4 twiddles (st 0..2 used)
#define WEXP_OFF 912    // [128*2] untangle W[k]=e^{-i pi k/256} (cos,-sin)
#define MELB_OFF 1168   // [80] int2 (base, nchunks)
#define WQ_OFF   1328   // [5*80 uint4 = 1600 floats] bf16 weights, [chunk][mel]
#define WS_FLOATS 2928  // 11712 B

// XOR swizzle on complex (float2) slot index: all 4 FFT stages hit the
// 4-lane-per-bank-pair floor for b64.
__device__ __forceinline__ int swz(int s) { return s ^ ((s >> 4) & 15); }

__device__ __forceinline__ ushort f2bf(float v) {   // RNE float->bf16
    unsigned b = __float_as_uint(v);
    return (ushort)((b + 0x7FFFu + ((b >> 16) & 1u)) >> 16);
}

__global__ __launch_bounds__(128)
void setup_kernel(float* __restrict__ ws)
{
    const int gid = blockIdx.x * 128 + threadIdx.x;   // grid 8 x 128
    const double ML = 1127.0 * log(1.0 + 20.0 / 700.0);
    const double MH = 1127.0 * log(1.0 + 8000.0 / 700.0);
    const double DD = (MH - ML) / (double)(NMELS + 1);

    if (gid < NWIN) {
        double a = 0.5 - 0.5 * cos(2.0 * M_PI * (double)gid / 399.0);
        if (a < 0.0) a = 0.0;
        ws[WIN_OFF + gid] = (float)pow(a, 0.85);
    } else if (gid >= 400 && gid < 485) {
        int e = gid - 400, st, j;
        if      (e < 64) { st = 0; j = e; }
        else if (e < 80) { st = 1; j = e - 64; }
        else if (e < 84) { st = 2; j = e - 80; }
        else             { st = 3; j = 0; }
        int Q = 64 >> (2 * st);
        double ang = -M_PI * (double)j / (2.0 * (double)Q);   // -2*pi*j/(4Q)
        float* t = ws + TWID_OFF + e * 6;
        t[0] = (float)cos(ang);       t[1] = (float)sin(ang);
        t[2] = (float)cos(2.0 * ang); t[3] = (float)sin(2.0 * ang);
        t[4] = (float)cos(3.0 * ang); t[5] = (float)sin(3.0 * ang);
    } else if (gid >= 512 && gid < 640) {
        int k = gid - 512;
        double th = M_PI * (double)k / 256.0;
        ws[WEXP_OFF + 2 * k]     = (float)cos(th);
        ws[WEXP_OFF + 2 * k + 1] = (float)(-sin(th));
    } else if (gid >= 640 && gid < 640 + NMELS) {
        int j = gid - 640;
        double mlo = ML + (double)j * DD;
        double mhi = mlo + 2.0 * DD;
        double flo = 700.0 * (exp(mlo / 1127.0) - 1.0);
        double fhi = 700.0 * (exp(mhi / 1127.0) - 1.0);
        int blo = max(1,   (int)(flo / 31.25));        // +-1 slack: weights clamp to 0
        int bhi = min(255, (int)(fhi / 31.25) + 1);
        int base = blo & ~7;
        int nc   = (bhi - base + 8) >> 3;              // <= 5
        ((int2*)(ws + MELB_OFF))[j] = make_int2(base, nc);
        uint4* wq = (uint4*)(ws + WQ_OFF);
        for (int c = 0; c < 5; ++c) {
            ushort tmp[8];
            for (int i = 0; i < 8; ++i) {
                int b = base + 8 * c + i;
                double u = (1127.0 * log(1.0 + (double)b * 31.25 / 700.0) - ML) / DD;
                double w = fmax(0.0, fmin(u - (double)j, (double)(j + 2) - u));
                tmp[i] = f2bf((float)w);               // 0 outside [blo,bhi]
            }
            uint4 v;
            v.x = (unsigned)tmp[0] | ((unsigned)tmp[1] << 16);
            v.y = (unsigned)tmp[2] | ((unsigned)tmp[3] << 16);
            v.z = (unsigned)tmp[4] | ((unsigned)tmp[5] << 16);
            v.w = (unsigned)tmp[6] | ((unsigned)tmp[7] << 16);
            wq[c * NMELS + j] = v;
        }
    }
}

template<bool USE_TAB>
__global__ __launch_bounds__(256)
void fbank_kernel(const float* __restrict__ wav, float* __restrict__ out,
                  const float* __restrict__ ws)
{
    __shared__ __align__(16) float  zbf[FPB][512];      // per-wave complex buffer (8192B)
    __shared__ __align__(16) float  pbuf[FPB][288];     // power spectrum + zero pad (4608B)
    __shared__ __align__(16) float  res[NMELS * FPB];   // logmel [mel][slot] (1280B)
    // total LDS = 14080 B -> 8 blocks/CU (full 32-wave occupancy cap)

    const int tid  = threadIdx.x;
    const int lane = tid & 63;
    const int wv   = tid >> 6;                 // one wave per frame
    const int bb   = blockIdx.x / BPB;
    const int f0   = (blockIdx.x % BPB) * FPB;
    const bool valid = (f0 + wv) < NFRM;

    const float MLf = 1127.0f * __logf(1.0f + 20.0f / 700.0f);
    const float MHf = 1127.0f * __logf(1.0f + 8000.0f / 700.0f);
    const float DDf = (MHf - MLf) / (float)(NMELS + 1);

    // zero the pbuf pad (bins 256..287) so aligned over-reads hit exact zeros
    if (lane < 32) pbuf[wv][256 + lane] = 0.0f;

    float*  zf = zbf[wv];
    float2* zc = (float2*)zf;

    // ---- preprocess: de-mean, pre-emphasis (2nd load), window; pack pairs ----
    if (valid) {
        const float* xp = wav + (size_t)bb * WLEN + (size_t)(f0 + wv) * NSHIFT;
        float xc[7], xm[7], wn[7];
        float s = 0.0f;
        #pragma unroll
        for (int t = 0; t < 7; ++t) {
            int n = 64 * t + lane;
            bool vn = (t < 6 || lane < 16);
            xc[t] = vn ? xp[n] : 0.0f;
            xm[t] = (vn && n > 0) ? xp[n - 1] : 0.0f;   // L1-hit reload
            if constexpr (USE_TAB) {
                wn[t] = vn ? ws[WIN_OFF + n] : 0.0f;    // L1-resident window
            } else {
                float a = fmaxf(0.5f - 0.5f * __cosf((float)n * (float)(2.0 * M_PI / 399.0)), 0.0f);
                wn[t] = __powf(a, 0.85f);
            }
            s += xc[t];
        }
        if (lane == 0) xm[0] = xc[0];                   // ref: prev[0] = x[0]
        #pragma unroll
        for (int off = 32; off > 0; off >>= 1) s += __shfl_xor(s, off, 64);
        const float mu3 = 0.03f * (s * (1.0f / (float)NWIN));
        #pragma unroll
        for (int t = 0; t < 7; ++t) {
            int n = 64 * t + lane;
            float y = 0.0f;
            if (t < 6 || lane < 16)
                y = (fmaf(-0.97f, xm[t], xc[t]) - mu3) * wn[t];
            zf[(swz(n >> 1) << 1) | (n & 1)] = y;       // n>=400 slots get 0
        }
        zf[(swz((448 + lane) >> 1) << 1) | (lane & 1)] = 0.0f;  // pad z[224..255]
    }

    // ---- 256-point radix-4 DIF FFT, in-place, digit-reversed output ----
    // Wave-private LDS: same-wave DS ordering + compiler lgkmcnt suffice.
    if (valid) {
        #pragma unroll
        for (int st = 0; st < 4; ++st) {
            const int Q = 64 >> (2 * st);                 // L/4
            int j  = lane & (Q - 1);
            int i0 = ((lane & ~(Q - 1)) << 2) + j;        // base + j
            float2 a0 = zc[swz(i0)];
            float2 a1 = zc[swz(i0 + Q)];
            float2 a2 = zc[swz(i0 + 2 * Q)];
            float2 a3 = zc[swz(i0 + 3 * Q)];
            float t0x = a0.x + a2.x, t0y = a0.y + a2.y;
            float t1x = a1.x + a3.x, t1y = a1.y + a3.y;
            float t2x = a0.x - a2.x, t2y = a0.y - a2.y;
            float t3x = a1.x - a3.x, t3y = a1.y - a3.y;
            float b0x = t0x + t1x, b0y = t0y + t1y;       // q=0
            float b2x = t0x - t1x, b2y = t0y - t1y;       // q=2
            float b1x = t2x + t3y, b1y = t2y - t3x;       // q=1: t2 - i*t3
            float b3x = t2x - t3y, b3y = t2y + t3x;       // q=3: t2 + i*t3
            if (st == 3) {
                // Q=1 -> j=0 -> all twiddles are exactly 1: pure butterfly
                zc[swz(i0)]     = make_float2(b0x, b0y);
                zc[swz(i0 + 1)] = make_float2(b1x, b1y);
                zc[swz(i0 + 2)] = make_float2(b2x, b2y);
                zc[swz(i0 + 3)] = make_float2(b3x, b3y);
            } else {
                float cn, sn, w2x, w2y, w3x, w3y;
                if constexpr (USE_TAB) {
                    constexpr int TOFF[4] = {0, 64, 80, 84};
                    const float* tw = ws + TWID_OFF + (TOFF[st] + j) * 6;
                    cn = tw[0]; sn = tw[1]; w2x = tw[2]; w2y = tw[3]; w3x = tw[4]; w3y = tw[5];
                } else {
                    float ang = (float)j * (float)(-M_PI / 2.0 / (double)Q);
                    __sincosf(ang, &sn, &cn);
                    w2x = cn * cn - sn * sn; w2y = 2.0f * cn * sn;
                    w3x = w2x * cn - w2y * sn; w3y = w2x * sn + w2y * cn;
                }
                zc[swz(i0)]       = make_float2(b0x, b0y);
                zc[swz(i0 + Q)]   = make_float2(fmaf(b1x, cn,  -b1y * sn),  fmaf(b1x, sn,  b1y * cn));
                zc[swz(i0 + 2*Q)] = make_float2(fmaf(b2x, w2x, -b2y * w2y), fmaf(b2x, w2y, b2y * w2x));
                zc[swz(i0 + 3*Q)] = make_float2(fmaf(b3x, w3x, -b3y * w3y), fmaf(b3x, w3y, b3y * w3x));
            }
        }
    }

    // ---- pair-symmetric untangle + power ----
    // X[k] = E + W*O, X[256-k] = conj(E - W*O); p = |X|^2.
    if (valid) {
        const int rl = ((lane & 3) << 6) | (((lane >> 2) & 3) << 4) | (((lane >> 4) & 3) << 2);
        #pragma unroll
        for (int r = 0; r < 2; ++r) {
            int k  = 64 * r + lane;
            int m8 = (256 - k) & 255;
            int rk = rl | r;
            int rm = ((m8 & 3) << 6) | (((m8 >> 2) & 3) << 4) | (((m8 >> 4) & 3) << 2) | ((m8 >> 6) & 3);
            float2 Zk = zc[swz(rk)];
            float2 Zm = zc[swz(rm)];
            float Sx = Zk.x + Zm.x, Sy = Zk.y - Zm.y;   // 2E
            float Ox = Zk.y + Zm.y, Oy = Zm.x - Zk.x;   // 2O
            float Wx, Wy;
            if constexpr (USE_TAB) {
                float2 w = ((const float2*)(ws + WEXP_OFF))[k];
                Wx = w.x; Wy = w.y;
            } else {
                __sincosf((float)k * (float)(-M_PI / 256.0), &Wy, &Wx);
            }
            float Ux = fmaf(Wx, Ox, -Wy * Oy), Uy = fmaf(Wx, Oy, Wy * Ox);  // 2*W*O
            float q1 = Sx + Ux, q2 = Sy + Uy;
            float q3 = Sx - Ux, q4 = Sy - Uy;
            pbuf[wv][k] = 0.25f * fmaf(q1, q1, q2 * q2);
            if (m8 != 0)                                  // m8==0 <=> bin 256 (weight 0)
                pbuf[wv][m8] = 0.25f * fmaf(q3, q3, q4 * q4);
        }
        if (lane == 0) {   // bin 128 self-paired: |X|^2 = |Z[128]|^2, rev4(128)=2
            float2 Z = zc[swz(2)];
            pbuf[wv][128] = fmaf(Z.x, Z.x, Z.y * Z.y);
        }
    }

    // ---- mel gather: pbuf 16B chunks from LDS, bf16 weights from global ----
    if (valid) {
        #pragma unroll
        for (int half = 0; half < 2; ++half) {
            int j = half * 64 + lane;
            if (j < NMELS) {
                float acc = 0.0f;
                if constexpr (USE_TAB) {
                    int2 mb = ((const int2*)(ws + MELB_OFF))[j];
                    const int base = mb.x, nc = mb.y;
                    const uint4* wq = (const uint4*)(ws + WQ_OFF);
                    for (int c = 0; c < nc; ++c) {
                        float4 p0 = *(const float4*)&pbuf[wv][base + 8 * c];
                        float4 p1 = *(const float4*)&pbuf[wv][base + 8 * c + 4];
                        uint4  wb = wq[c * NMELS + j];   // coalesced, L1/L2-resident
                        acc = fmaf(__uint_as_float(wb.x << 16),          p0.x, acc);
                        acc = fmaf(__uint_as_float(wb.x & 0xffff0000u),  p0.y, acc);
                        acc = fmaf(__uint_as_float(wb.y << 16),          p0.z, acc);
                        acc = fmaf(__uint_as_float(wb.y & 0xffff0000u),  p0.w, acc);
                        acc = fmaf(__uint_as_float(wb.z << 16),          p1.x, acc);
                        acc = fmaf(__uint_as_float(wb.z & 0xffff0000u),  p1.y, acc);
                        acc = fmaf(__uint_as_float(wb.w << 16),          p1.z, acc);
                        acc = fmaf(__uint_as_float(wb.w & 0xffff0000u),  p1.w, acc);
                    }
                } else {
                    float mlo = MLf + (float)j * DDf;
                    float mhi = mlo + 2.0f * DDf;
                    float flo = 700.0f * (__expf(mlo * (1.0f / 1127.0f)) - 1.0f);
                    float fhi = 700.0f * (__expf(mhi * (1.0f / 1127.0f)) - 1.0f);
                    int blo = max(1,   (int)(flo * (1.0f / 31.25f)));
                    int bhi = min(255, (int)(fhi * (1.0f / 31.25f)) + 1);
                    for (int b = blo; b <= bhi; ++b) {
                        float u = (1127.0f * __logf(1.0f + (float)b * (31.25f / 700.0f)) - MLf) / DDf;
                        float w = fmaxf(0.0f, fminf(u - (float)j, (float)(j + 2) - u));
                        acc = fmaf(w, pbuf[wv][b], acc);
                    }
                }
                res[j * FPB + wv] = __logf(fmaxf(acc, EPSV));
            }
        }
    }
    __syncthreads();

    // ---- transposed output, 8B bursts ----
    const int nval = min(FPB, NFRM - f0);
    if (tid < NMELS) {
        size_t o = ((size_t)bb * NMELS + tid) * NFRM + (size_t)f0;
        *(float2*)&out[o] = make_float2(res[tid * 4 + 0], res[tid * 4 + 1]);
        if (nval == 4)
            *(float2*)&out[o + 2] = make_float2(res[tid * 4 + 2], res[tid * 4 + 3]);
    }
}

extern "C" void kernel_launch(void* const* d_in, const int* in_sizes, int n_in,
                              void* d_out, int out_size, void* d_ws, size_t ws_size,
                              hipStream_t stream)
{
    const float* wav = (const float*)d_in[0];
    float* out = (float*)d_out;
    float* ws  = (float*)d_ws;
    if (ws != nullptr && ws_size >= WS_FLOATS * sizeof(float)) {
        setup_kernel<<<dim3(8), dim3(128), 0, stream>>>(ws);
        fbank_kernel<true><<<dim3(32 * BPB), dim3(256), 0, stream>>>(wav, out, ws);
    } else {
        fbank_kernel<false><<<dim3(32 * BPB), dim3(256), 0, stream>>>(wav, out, ws);
    }
}

// Round 9
// 53.937 us; speedup vs baseline: 1.0773x; 1.0327x over previous
//
#include <hip/hip_runtime.h>
#include <math.h>

#ifndef M_PI
#define M_PI 3.14159265358979323846
#endif

#define NWIN   400
#define NSHIFT 160
#define NMELS  80
#define NFRM   998
#define WLEN   160000
#define FPB    4
#define BPB    250          // frame-blocks per batch (249 full + 1 tail of 2)
#define EPSV   1.1920929e-07f

// workspace layout (float units)
#define WIN_OFF  0      // [400]      Povey window
#define TW16_OFF 400    // [3*64 f2]  W_16^{a*c}, c=1..3, a=lane&3
#define TWA_OFF  784    // [4*64 f2]  inter-pass W_256^{q*(c+4*rev2(a))}
#define WEXP_OFF 1296   // [128 f2]   untangle W[k]=e^{-i pi k/256}
#define MELB_OFF 1552   // [80] int2 (base, nchunks)
#define WQ_OFF   1712   // [5*80 uint4] bf16 mel weights, [chunk][mel]
#define WS_FLOATS 3312  // 13248 B

// DPP quad_perm cross-lane (VALU pipe, no LDS, no address math)
#define DPPF(v, ctrl) __int_as_float(__builtin_amdgcn_mov_dpp(__float_as_int(v), ctrl, 0xF, 0xF, true))
// xor2 within quad: [2,3,0,1] = 0x4E ; xor1: [1,0,3,2] = 0xB1

__device__ __forceinline__ ushort f2bf(float v) {   // RNE float->bf16
    unsigned b = __float_as_uint(v);
    return (ushort)((b + 0x7FFFu + ((b >> 16) & 1u)) >> 16);
}

// DFT-16: radix-4 over local slots (sub-idx b), W16^{ac} twiddle, radix-4
// across the quad (sub-idx a) via DPP. Input: slot b holds x[a+4b] (a=lane&3).
// Output: slot c holds Y[c + 4*rev2(a)].  (Verified on delta_0/delta_1 by hand.)
__device__ __forceinline__ void dft16_quad(float zx[4], float zy[4],
    float2 w1, float2 w2, float2 w3, bool b1, bool b2, bool b3)
{
    float t0x = zx[0]+zx[2], t0y = zy[0]+zy[2];
    float t1x = zx[1]+zx[3], t1y = zy[1]+zy[3];
    float t2x = zx[0]-zx[2], t2y = zy[0]-zy[2];
    float t3x = zx[1]-zx[3], t3y = zy[1]-zy[3];
    float p0x = t0x+t1x, p0y = t0y+t1y;
    float p2x = t0x-t1x, p2y = t0y-t1y;
    float p1x = t2x+t3y, p1y = t2y-t3x;          // W4 = -i
    float p3x = t2x-t3y, p3y = t2y+t3x;
    zx[0] = p0x;                     zy[0] = p0y;
    zx[1] = p1x*w1.x - p1y*w1.y;     zy[1] = p1x*w1.y + p1y*w1.x;
    zx[2] = p2x*w2.x - p2y*w2.y;     zy[2] = p2x*w2.y + p2y*w2.x;
    zx[3] = p3x*w3.x - p3y*w3.y;     zy[3] = p3x*w3.y + p3y*w3.x;
    #pragma unroll
    for (int c = 0; c < 4; ++c) {
        float vx = zx[c], vy = zy[c];
        float ex = DPPF(vx, 0x4E), ey = DPPF(vy, 0x4E);   // partner a^2
        float ux = b2 ? (ex - vx) : (vx + ex);
        float uy = b2 ? (ey - vy) : (vy + ey);
        float rx = b3 ? uy : ux;                          // *(-i) on lane a==3
        float ry = b3 ? (0.0f - ux) : uy;
        float fx = DPPF(rx, 0xB1), fy = DPPF(ry, 0xB1);   // partner a^1
        zx[c] = b1 ? (fx - rx) : (rx + fx);
        zy[c] = b1 ? (fy - ry) : (ry + fy);
    }
}

__global__ __launch_bounds__(128)
void setup_kernel(float* __restrict__ ws)
{
    const int gid = blockIdx.x * 128 + threadIdx.x;   // grid 9 x 128
    const double ML = 1127.0 * log(1.0 + 20.0 / 700.0);
    const double MH = 1127.0 * log(1.0 + 8000.0 / 700.0);
    const double DD = (MH - ML) / (double)(NMELS + 1);

    if (gid < NWIN) {
        double a = 0.5 - 0.5 * cos(2.0 * M_PI * (double)gid / 399.0);
        if (a < 0.0) a = 0.0;
        ws[WIN_OFF + gid] = (float)pow(a, 0.85);
    } else if (gid < 592) {                       // TW16: e = (c-1)*64 + lane
        int e = gid - 400, a = e & 3, c = (e >> 6) + 1;
        double th = -M_PI * (double)(a * c) / 8.0;
        ws[TW16_OFF + 2 * e]     = (float)cos(th);
        ws[TW16_OFF + 2 * e + 1] = (float)sin(th);
    } else if (gid < 848) {                       // TWA: e = c*64 + lane
        int e = gid - 592, L = e & 63, c = e >> 6;
        int q = L >> 2, a = L & 3;
        int r2 = ((a & 1) << 1) | (a >> 1);
        double th = -M_PI * (double)(q * (c + 4 * r2)) / 128.0;
        ws[TWA_OFF + 2 * e]     = (float)cos(th);
        ws[TWA_OFF + 2 * e + 1] = (float)sin(th);
    } else if (gid < 976) {                       // WEXP
        int k = gid - 848;
        double th = M_PI * (double)k / 256.0;
        ws[WEXP_OFF + 2 * k]     = (float)cos(th);
        ws[WEXP_OFF + 2 * k + 1] = (float)(-sin(th));
    } else if (gid >= 1024 && gid < 1024 + NMELS) {
        int j = gid - 1024;
        double mlo = ML + (double)j * DD;
        double mhi = mlo + 2.0 * DD;
        double flo = 700.0 * (exp(mlo / 1127.0) - 1.0);
        double fhi = 700.0 * (exp(mhi / 1127.0) - 1.0);
        int blo = max(1,   (int)(flo / 31.25));   // +-1 slack: weights clamp to 0
        int bhi = min(255, (int)(fhi / 31.25) + 1);
        int base = blo & ~7;
        int nc   = (bhi - base + 8) >> 3;         // <= 5
        ((int2*)(ws + MELB_OFF))[j] = make_int2(base, nc);
        uint4* wq = (uint4*)(ws + WQ_OFF);
        for (int c = 0; c < 5; ++c) {
            ushort tmp[8];
            for (int i = 0; i < 8; ++i) {
                int b = base + 8 * c + i;
                double u = (1127.0 * log(1.0 + (double)b * 31.25 / 700.0) - ML) / DD;
                double w = fmax(0.0, fmin(u - (double)j, (double)(j + 2) - u));
                tmp[i] = f2bf((float)w);
            }
            uint4 v;
            v.x = (unsigned)tmp[0] | ((unsigned)tmp[1] << 16);
            v.y = (unsigned)tmp[2] | ((unsigned)tmp[3] << 16);
            v.z = (unsigned)tmp[4] | ((unsigned)tmp[5] << 16);
            v.w = (unsigned)tmp[6] | ((unsigned)tmp[7] << 16);
            wq[c * NMELS + j] = v;
        }
    }
}

template<bool USE_TAB>
__global__ __launch_bounds__(256, 8)
void fbank_kernel(const float* __restrict__ wav, float* __restrict__ out,
                  const float* __restrict__ ws)
{
    __shared__ __align__(16) float zbf[FPB][512];   // y / z input, then X output
    __shared__ __align__(16) float ibf[FPB][512];   // inter-pass B[], then pbuf
    __shared__ __align__(16) float res[NMELS * FPB];
    // LDS = 8192 + 8192 + 1280 = 17664 B -> 8 blocks/CU (full wave cap)

    const int tid  = threadIdx.x;
    const int lane = tid & 63;
    const int wv   = tid >> 6;                 // one wave per frame
    const int bb   = blockIdx.x / BPB;
    const int f0   = (blockIdx.x % BPB) * FPB;
    const bool valid = (f0 + wv) < NFRM;

    const float MLf = 1127.0f * __logf(1.0f + 20.0f / 700.0f);
    const float MHf = 1127.0f * __logf(1.0f + 8000.0f / 700.0f);
    const float DDf = (MHf - MLf) / (float)(NMELS + 1);

    float* zf = zbf[wv];

    // ---- preprocess: de-mean, pre-emphasis, window; LINEAR y writes ----
    if (valid) {
        const float* xp = wav + (size_t)bb * WLEN + (size_t)(f0 + wv) * NSHIFT;
        float xc[7], xm[7], wn[7];
        float s = 0.0f;
        #pragma unroll
        for (int t = 0; t < 7; ++t) {
            int n = 64 * t + lane;
            bool vn = (t < 6 || lane < 16);
            xc[t] = vn ? xp[n] : 0.0f;
            xm[t] = (vn && n > 0) ? xp[n - 1] : 0.0f;   // L1-hit reload
            if constexpr (USE_TAB) {
                wn[t] = vn ? ws[WIN_OFF + n] : 0.0f;
            } else {
                float aa = fmaxf(0.5f - 0.5f * __cosf((float)n * (float)(2.0 * M_PI / 399.0)), 0.0f);
                wn[t] = __powf(aa, 0.85f);
            }
            s += xc[t];
        }
        if (lane == 0) xm[0] = xc[0];                   // ref: prev[0] = x[0]
        #pragma unroll
        for (int off = 32; off > 0; off >>= 1) s += __shfl_xor(s, off, 64);
        const float mu3 = 0.03f * (s * (1.0f / (float)NWIN));
        #pragma unroll
        for (int t = 0; t < 7; ++t) {
            bool vn = (t < 6 || lane < 16);
            float y = vn ? (fmaf(-0.97f, xm[t], xc[t]) - mu3) * wn[t] : 0.0f;
            zf[64 * t + lane] = y;                      // linear: 2-way, free
        }
        zf[448 + lane] = 0.0f;                          // pad y[448..511]
    }

    // ---- 256-pt complex FFT as radix-16 x radix-16, quad-DPP butterflies ----
    // z[m] = y[2m] + i*y[2m+1] (a float2 view of linear y).
    // Pass A: DFT16 over n2 (z[n1+16*n2]); inter twiddle W_256^{n1*k1};
    // Pass B: DFT16 over n1 -> X in NATURAL frequency order.
    if (valid) {
        const int a  = lane & 3, q = lane >> 2;
        const int r2 = ((a & 1) << 1) | (a >> 1);       // rev2(a)
        const bool b1 = (a & 1) != 0, b2 = (a & 2) != 0, b3 = (a == 3);
        float2 w1, w2, w3, ta[4];
        if constexpr (USE_TAB) {
            const float2* t16 = (const float2*)(ws + TW16_OFF);
            w1 = t16[lane]; w2 = t16[64 + lane]; w3 = t16[128 + lane];
            const float2* twa = (const float2*)(ws + TWA_OFF);
            #pragma unroll
            for (int c = 0; c < 4; ++c) ta[c] = twa[c * 64 + lane];
        } else {
            float s1, c1;
            __sincosf((float)a * (float)(-M_PI / 8.0), &s1, &c1);
            w1 = make_float2(c1, s1);
            w2 = make_float2(w1.x*w1.x - w1.y*w1.y, 2.0f*w1.x*w1.y);
            w3 = make_float2(w2.x*w1.x - w2.y*w1.y, w2.x*w1.y + w2.y*w1.x);
            float sb, cb, ss, cs;
            __sincosf((float)(q * 4 * r2) * (float)(-M_PI / 128.0), &sb, &cb);
            __sincosf((float)q * (float)(-M_PI / 128.0), &ss, &cs);
            ta[0] = make_float2(cb, sb);
            #pragma unroll
            for (int c = 1; c < 4; ++c)
                ta[c] = make_float2(ta[c-1].x*cs - ta[c-1].y*ss,
                                    ta[c-1].x*ss + ta[c-1].y*cs);
        }
        float2* zc = (float2*)zbf[wv];
        float2* ic = (float2*)ibf[wv];
        float zx[4], zy[4];
        // pass A: read z[q + 16a + 64b]  (base + imm, 4 lanes/bank-pair floor)
        const int ra = q + 16 * a;
        #pragma unroll
        for (int b = 0; b < 4; ++b) { float2 v = zc[ra + 64*b]; zx[b] = v.x; zy[b] = v.y; }
        dft16_quad(zx, zy, w1, w2, w3, b1, b2, b3);
        // inter twiddle + swizzled transpose write: B[n1=q][k1=c+4*r2] -> [16*k1+n1]
        #pragma unroll
        for (int c = 0; c < 4; ++c) {
            float bx = zx[c]*ta[c].x - zy[c]*ta[c].y;
            float by = zx[c]*ta[c].y + zy[c]*ta[c].x;
            int idx = 16*c + 64*r2 + q;
            ic[idx ^ ((idx >> 4) & 15)] = make_float2(bx, by);
        }
        // pass B: read B[n1=a+4b][k1=q]
        #pragma unroll
        for (int b = 0; b < 4; ++b) {
            int idx = 16*q + a + 4*b;
            float2 v = ic[idx ^ ((idx >> 4) & 15)];
            zx[b] = v.x; zy[b] = v.y;
        }
        dft16_quad(zx, zy, w1, w2, w3, b1, b2, b3);
        // X[k1 + 16*k2], k1=q, k2=c+4*r2 -> natural-order write (imm offsets)
        #pragma unroll
        for (int c = 0; c < 4; ++c)
            zc[q + 16*c + 64*r2] = make_float2(zx[c], zy[c]);
    }

    // ---- pair-symmetric untangle + power (natural indices, linear LDS) ----
    float* pw = ibf[wv];                                // pbuf overlay (B[] dead)
    if (valid) {
        float2* zc = (float2*)zbf[wv];
        if (lane < 32) pw[256 + lane] = 0.0f;           // pad for gather over-read
        #pragma unroll
        for (int r = 0; r < 2; ++r) {
            int k  = 64 * r + lane;
            int m8 = (256 - k) & 255;
            float2 Zk = zc[k];
            float2 Zm = zc[m8];
            float Sx = Zk.x + Zm.x, Sy = Zk.y - Zm.y;   // 2E
            float Ox = Zk.y + Zm.y, Oy = Zm.x - Zk.x;   // 2O
            float Wx, Wy;
            if constexpr (USE_TAB) {
                float2 w = ((const float2*)(ws + WEXP_OFF))[k];
                Wx = w.x; Wy = w.y;
            } else {
                __sincosf((float)k * (float)(-M_PI / 256.0), &Wy, &Wx);
            }
            float Ux = fmaf(Wx, Ox, -Wy * Oy), Uy = fmaf(Wx, Oy, Wy * Ox);
            float q1 = Sx + Ux, q2 = Sy + Uy;
            float q3 = Sx - Ux, q4 = Sy - Uy;
            pw[k] = 0.25f * fmaf(q1, q1, q2 * q2);
            if (m8 != 0)                                // bin 256 has weight 0
                pw[m8] = 0.25f * fmaf(q3, q3, q4 * q4);
        }
        if (lane == 0) {                                // bin 128 self-paired
            float2 Z = ((float2*)zbf[wv])[128];
            pw[128] = fmaf(Z.x, Z.x, Z.y * Z.y);
        }
    }

    // ---- mel gather: pw 16B chunks from LDS, bf16 weights from global ----
    if (valid) {
        #pragma unroll
        for (int half = 0; half < 2; ++half) {
            int j = half * 64 + lane;
            if (j < NMELS) {
                float acc = 0.0f;
                if constexpr (USE_TAB) {
                    int2 mb = ((const int2*)(ws + MELB_OFF))[j];
                    const int base = mb.x, nc = mb.y;
                    const uint4* wq = (const uint4*)(ws + WQ_OFF);
                    for (int c = 0; c < nc; ++c) {
                        float4 p0 = *(const float4*)&pw[base + 8 * c];
                        float4 p1 = *(const float4*)&pw[base + 8 * c + 4];
                        uint4  wb = wq[c * NMELS + j];  // coalesced, L1-resident
                        acc = fmaf(__uint_as_float(wb.x << 16),          p0.x, acc);
                        acc = fmaf(__uint_as_float(wb.x & 0xffff0000u),  p0.y, acc);
                        acc = fmaf(__uint_as_float(wb.y << 16),          p0.z, acc);
                        acc = fmaf(__uint_as_float(wb.y & 0xffff0000u),  p0.w, acc);
                        acc = fmaf(__uint_as_float(wb.z << 16),          p1.x, acc);
                        acc = fmaf(__uint_as_float(wb.z & 0xffff0000u),  p1.y, acc);
                        acc = fmaf(__uint_as_float(wb.w << 16),          p1.z, acc);
                        acc = fmaf(__uint_as_float(wb.w & 0xffff0000u),  p1.w, acc);
                    }
                } else {
                    float mlo = MLf + (float)j * DDf;
                    float mhi = mlo + 2.0f * DDf;
                    float flo = 700.0f * (__expf(mlo * (1.0f / 1127.0f)) - 1.0f);
                    float fhi = 700.0f * (__expf(mhi * (1.0f / 1127.0f)) - 1.0f);
                    int blo = max(1,   (int)(flo * (1.0f / 31.25f)));
                    int bhi = min(255, (int)(fhi * (1.0f / 31.25f)) + 1);
                    for (int b = blo; b <= bhi; ++b) {
                        float u = (1127.0f * __logf(1.0f + (float)b * (31.25f / 700.0f)) - MLf) / DDf;
                        float w = fmaxf(0.0f, fminf(u - (float)j, (float)(j + 2) - u));
                        acc = fmaf(w, pw[b], acc);
                    }
                }
                res[j * FPB + wv] = __logf(fmaxf(acc, EPSV));
            }
        }
    }
    __syncthreads();

    // ---- transposed output, 8B bursts ----
    const int nval = min(FPB, NFRM - f0);
    if (tid < NMELS) {
        size_t o = ((size_t)bb * NMELS + tid) * NFRM + (size_t)f0;
        *(float2*)&out[o] = make_float2(res[tid * 4 + 0], res[tid * 4 + 1]);
        if (nval == 4)
            *(float2*)&out[o + 2] = make_float2(res[tid * 4 + 2], res[tid * 4 + 3]);
    }
}

extern "C" void kernel_launch(void* const* d_in, const int* in_sizes, int n_in,
                              void* d_out, int out_size, void* d_ws, size_t ws_size,
                              hipStream_t stream)
{
    const float* wav = (const float*)d_in[0];
    float* out = (float*)d_out;
    float* ws  = (float*)d_ws;
    if (ws != nullptr && ws_size >= WS_FLOATS * sizeof(float)) {
        setup_kernel<<<dim3(9), dim3(128), 0, stream>>>(ws);
        fbank_kernel<true><<<dim3(32 * BPB), dim3(256), 0, stream>>>(wav, out, ws);
    } else {
        fbank_kernel<false><<<dim3(32 * BPB), dim3(256), 0, stream>>>(wav, out, ws);
    }
}

// Round 10
// 47.401 us; speedup vs baseline: 1.2258x; 1.1379x over previous
//
#include <hip/hip_runtime.h>
#include <math.h>

#define NWIN   400
#define NSHIFT 160
#define NMELS  80
#define NFRM   998
#define WLEN   160000
#define FPB    4
#define BPB    250          // frame-blocks per batch (249 full + 1 tail of 2)
#define EPSV   1.1920929e-07f

// ================= compile-time table generation (no setup kernel) ==========
constexpr double KPI = 3.14159265358979323846;

constexpr double kcos(double x) {           // |x| <= 7, err < 1e-14
    double x2 = x * x, t = 1.0, s = 1.0;
    for (int k = 1; k <= 22; ++k) { t *= -x2 / (double)((2*k-1)*(2*k)); s += t; }
    return s;
}
constexpr double ksin(double x) {
    double x2 = x * x, t = x, s = x;
    for (int k = 1; k <= 22; ++k) { t *= -x2 / (double)((2*k)*(2*k+1)); s += t; }
    return s;
}
constexpr double kln(double a) {            // a > 0
    double m = a; int e = 0;
    while (m < 0.70710678118654752) { m *= 2.0; --e; }
    while (m >= 1.41421356237309505) { m *= 0.5; ++e; }
    double z = (m - 1.0) / (m + 1.0), z2 = z * z, t = z, s = 0.0;
    for (int k = 0; k <= 14; ++k) { s += t / (double)(2*k+1); t *= z2; }
    return 2.0 * s + (double)e * 0.69314718055994530942;
}
constexpr double kexp(double y) {           // |y| <= 10
    int n = (int)(y * 1.4426950408889634 + (y >= 0.0 ? 0.5 : -0.5));
    double r = y - (double)n * 0.69314718055994530942;
    double t = 1.0, s = 1.0;
    for (int k = 1; k <= 16; ++k) { t *= r / (double)k; s += t; }
    double p = 1.0;
    int an = n >= 0 ? n : -n;
    for (int i = 0; i < an; ++i) p *= (n >= 0 ? 2.0 : 0.5);
    return s * p;
}

struct alignas(16) WinT  { float v[NWIN]; };
struct alignas(16) Tw16T { float v[3][64][2]; };
struct alignas(16) TwaT  { float v[4][64][2]; };
struct alignas(16) WexpT { float v[128][2]; };
struct alignas(16) MelT  { int base[NMELS]; float w[5][NMELS][8]; };

constexpr WinT make_win() {
    WinT t{};
    for (int n = 0; n < NWIN; ++n) {
        double a = 0.5 - 0.5 * kcos(2.0 * KPI * (double)n / 399.0);
        if (a < 0.0) a = 0.0;
        t.v[n] = (a <= 0.0) ? 0.0f : (float)kexp(0.85 * kln(a));  // a^0.85
    }
    return t;
}
constexpr Tw16T make_tw16() {
    Tw16T t{};
    for (int c = 1; c <= 3; ++c)
        for (int L = 0; L < 64; ++L) {
            int a = L & 3;
            double th = -KPI * (double)(a * c) / 8.0;
            t.v[c-1][L][0] = (float)kcos(th);
            t.v[c-1][L][1] = (float)ksin(th);
        }
    return t;
}
constexpr TwaT make_twa() {
    TwaT t{};
    for (int c = 0; c < 4; ++c)
        for (int L = 0; L < 64; ++L) {
            int q = L >> 2, a = L & 3;
            int r2 = ((a & 1) << 1) | (a >> 1);
            double th = -KPI * (double)(q * (c + 4 * r2)) / 128.0;
            t.v[c][L][0] = (float)kcos(th);
            t.v[c][L][1] = (float)ksin(th);
        }
    return t;
}
constexpr WexpT make_wexp() {
    WexpT t{};
    for (int k = 0; k < 128; ++k) {
        double th = KPI * (double)k / 256.0;
        t.v[k][0] = (float)kcos(th);
        t.v[k][1] = (float)(-ksin(th));
    }
    return t;
}
constexpr MelT make_mel() {
    MelT t{};
    double ML = 1127.0 * kln(1.0 + 20.0 / 700.0);
    double MH = 1127.0 * kln(1.0 + 8000.0 / 700.0);
    double DD = (MH - ML) / 81.0;
    for (int j = 0; j < NMELS; ++j) {
        double mlo = ML + (double)j * DD;
        double flo = 700.0 * (kexp(mlo / 1127.0) - 1.0);
        int blo = (int)(flo / 31.25); if (blo < 1) blo = 1;
        int base = blo & ~7;                 // aligned; spans fit in 5 chunks
        t.base[j] = base;
        for (int c = 0; c < 5; ++c)
            for (int i = 0; i < 8; ++i) {
                int b = base + 8 * c + i;
                double w = 0.0;
                if (b >= 1 && b <= 255) {
                    double u = (1127.0 * kln(1.0 + (double)b * 31.25 / 700.0) - ML) / DD;
                    double lo = u - (double)j, hi = (double)(j + 2) - u;
                    w = lo < hi ? lo : hi;
                    if (w < 0.0) w = 0.0;    // triangle clamps outside [blo,bhi]
                }
                t.w[c][j][i] = (float)w;
            }
    }
    return t;
}

__device__ constexpr WinT  g_win  = make_win();
__device__ constexpr Tw16T g_tw16 = make_tw16();
__device__ constexpr TwaT  g_twa  = make_twa();
__device__ constexpr WexpT g_wexp = make_wexp();
__device__ constexpr MelT  g_mel  = make_mel();

// ============================================================================
// DPP quad_perm cross-lane (VALU pipe, no LDS, no address math)
#define DPPF(v, ctrl) __int_as_float(__builtin_amdgcn_mov_dpp(__float_as_int(v), ctrl, 0xF, 0xF, true))
// xor2 within quad: [2,3,0,1] = 0x4E ; xor1: [1,0,3,2] = 0xB1

// DFT-16: radix-4 over local slots (sub-idx b), W16^{ac} twiddle, radix-4
// across the quad (sub-idx a) via DPP. Input: slot b holds x[a+4b] (a=lane&3).
// Output: slot c holds Y[c + 4*rev2(a)].
__device__ __forceinline__ void dft16_quad(float zx[4], float zy[4],
    float2 w1, float2 w2, float2 w3, bool b1, bool b2, bool b3)
{
    float t0x = zx[0]+zx[2], t0y = zy[0]+zy[2];
    float t1x = zx[1]+zx[3], t1y = zy[1]+zy[3];
    float t2x = zx[0]-zx[2], t2y = zy[0]-zy[2];
    float t3x = zx[1]-zx[3], t3y = zy[1]-zy[3];
    float p0x = t0x+t1x, p0y = t0y+t1y;
    float p2x = t0x-t1x, p2y = t0y-t1y;
    float p1x = t2x+t3y, p1y = t2y-t3x;          // W4 = -i
    float p3x = t2x-t3y, p3y = t2y+t3x;
    zx[0] = p0x;                     zy[0] = p0y;
    zx[1] = p1x*w1.x - p1y*w1.y;     zy[1] = p1x*w1.y + p1y*w1.x;
    zx[2] = p2x*w2.x - p2y*w2.y;     zy[2] = p2x*w2.y + p2y*w2.x;
    zx[3] = p3x*w3.x - p3y*w3.y;     zy[3] = p3x*w3.y + p3y*w3.x;
    #pragma unroll
    for (int c = 0; c < 4; ++c) {
        float vx = zx[c], vy = zy[c];
        float ex = DPPF(vx, 0x4E), ey = DPPF(vy, 0x4E);   // partner a^2
        float ux = ex + (b2 ? -vx : vx);                  // cndmask w/ neg mod
        float uy = ey + (b2 ? -vy : vy);
        float rx = b3 ? uy : ux;                          // *(-i) on lane a==3
        float ry = b3 ? -ux : uy;
        float fx = DPPF(rx, 0xB1), fy = DPPF(ry, 0xB1);   // partner a^1
        zx[c] = fx + (b1 ? -rx : rx);
        zy[c] = fy + (b1 ? -ry : ry);
    }
}

__global__ __launch_bounds__(256, 8)
void fbank_kernel(const float* __restrict__ wav, float* __restrict__ out)
{
    __shared__ __align__(16) float zbf[FPB][512];   // y / z input, then X output
    __shared__ __align__(16) float ibf[FPB][512];   // inter-pass B[], then pbuf
    __shared__ __align__(16) float res[NMELS * FPB];
    // LDS = 17664 B -> 8 blocks/CU (full 32-wave cap)

    const int tid  = threadIdx.x;
    const int lane = tid & 63;
    const int wv   = tid >> 6;                 // one wave per frame
    const int bb   = blockIdx.x / BPB;
    const int f0   = (blockIdx.x % BPB) * FPB;
    const bool valid = (f0 + wv) < NFRM;

    float* zf = zbf[wv];

    // ---- preprocess: de-mean, pre-emphasis, window; LINEAR y writes ----
    if (valid) {
        const float* xp = wav + (size_t)bb * WLEN + (size_t)(f0 + wv) * NSHIFT;
        float xc[7], xm[7], wn[7];
        float s = 0.0f;
        #pragma unroll
        for (int t = 0; t < 7; ++t) {
            int n = 64 * t + lane;
            bool vn = (t < 6 || lane < 16);
            xc[t] = vn ? xp[n] : 0.0f;
            xm[t] = (vn && n > 0) ? xp[n - 1] : 0.0f;   // L1-hit reload
            wn[t] = vn ? g_win.v[n] : 0.0f;
            s += xc[t];
        }
        if (lane == 0) xm[0] = xc[0];                   // ref: prev[0] = x[0]
        #pragma unroll
        for (int off = 32; off > 0; off >>= 1) s += __shfl_xor(s, off, 64);
        const float mu3 = 0.03f * (s * (1.0f / (float)NWIN));
        #pragma unroll
        for (int t = 0; t < 7; ++t) {
            bool vn = (t < 6 || lane < 16);
            float y = vn ? (fmaf(-0.97f, xm[t], xc[t]) - mu3) * wn[t] : 0.0f;
            zf[64 * t + lane] = y;                      // linear: 2-way, free
        }
        zf[448 + lane] = 0.0f;                          // pad y[448..511]
    }

    // ---- 256-pt complex FFT as radix-16 x radix-16, quad-DPP butterflies ----
    // z[m] = y[2m] + i*y[2m+1] (float2 view of linear y).
    // Pass A: DFT16 over n2; inter twiddle W_256^{n1*k1}; Pass B: DFT16 over
    // n1 -> X in natural frequency order.
    if (valid) {
        const int a  = lane & 3, q = lane >> 2;
        const int r2 = ((a & 1) << 1) | (a >> 1);       // rev2(a)
        const bool b1 = (a & 1) != 0, b2 = (a & 2) != 0, b3 = (a == 3);
        const float2* t16 = (const float2*)g_tw16.v;
        float2 w1 = t16[lane], w2 = t16[64 + lane], w3 = t16[128 + lane];
        const float2* twa = (const float2*)g_twa.v;
        float2 ta[4];
        #pragma unroll
        for (int c = 0; c < 4; ++c) ta[c] = twa[c * 64 + lane];

        float2* zc = (float2*)zbf[wv];
        float2* ic = (float2*)ibf[wv];
        float zx[4], zy[4];
        // pass A: read z[q + 16a + 64b]  (4 lanes/bank-pair floor)
        const int ra = q + 16 * a;
        #pragma unroll
        for (int b = 0; b < 4; ++b) { float2 v = zc[ra + 64*b]; zx[b] = v.x; zy[b] = v.y; }
        dft16_quad(zx, zy, w1, w2, w3, b1, b2, b3);
        // inter twiddle + swizzled transpose write: B[n1=q][k1=c+4*r2]
        #pragma unroll
        for (int c = 0; c < 4; ++c) {
            float bx = zx[c]*ta[c].x - zy[c]*ta[c].y;
            float by = zx[c]*ta[c].y + zy[c]*ta[c].x;
            int idx = 16*c + 64*r2 + q;
            ic[idx ^ ((idx >> 4) & 15)] = make_float2(bx, by);
        }
        // pass B: read B[n1=a+4b][k1=q]
        #pragma unroll
        for (int b = 0; b < 4; ++b) {
            int idx = 16*q + a + 4*b;
            float2 v = ic[idx ^ ((idx >> 4) & 15)];
            zx[b] = v.x; zy[b] = v.y;
        }
        dft16_quad(zx, zy, w1, w2, w3, b1, b2, b3);
        // X[k1 + 16*k2], k1=q, k2=c+4*r2 -> natural-order write
        #pragma unroll
        for (int c = 0; c < 4; ++c)
            zc[q + 16*c + 64*r2] = make_float2(zx[c], zy[c]);
    }

    // ---- pair-symmetric untangle + power (natural indices, linear LDS) ----
    float* pw = ibf[wv];                                // pbuf overlay (B[] dead)
    if (valid) {
        float2* zc = (float2*)zbf[wv];
        if (lane < 32) pw[256 + lane] = 0.0f;           // pad for gather over-read
        const float2* we = (const float2*)g_wexp.v;
        #pragma unroll
        for (int r = 0; r < 2; ++r) {
            int k  = 64 * r + lane;
            int m8 = (256 - k) & 255;
            float2 Zk = zc[k];
            float2 Zm = zc[m8];
            float Sx = Zk.x + Zm.x, Sy = Zk.y - Zm.y;   // 2E
            float Ox = Zk.y + Zm.y, Oy = Zm.x - Zk.x;   // 2O
            float2 w = we[k];
            float Ux = fmaf(w.x, Ox, -w.y * Oy), Uy = fmaf(w.x, Oy, w.y * Ox);
            float q1 = Sx + Ux, q2 = Sy + Uy;
            float q3 = Sx - Ux, q4 = Sy - Uy;
            pw[k] = 0.25f * fmaf(q1, q1, q2 * q2);
            if (m8 != 0)                                // bin 256 has weight 0
                pw[m8] = 0.25f * fmaf(q3, q3, q4 * q4);
        }
        if (lane == 0) {                                // bin 128 self-paired
            float2 Z = ((float2*)zbf[wv])[128];
            pw[128] = fmaf(Z.x, Z.x, Z.y * Z.y);
        }
    }

    // ---- mel gather: fixed 5 chunks, fully unrolled, f32 weights ----
    if (valid) {
        #pragma unroll
        for (int half = 0; half < 2; ++half) {
            int j = half * 64 + lane;
            if (j < NMELS) {
                const int base = g_mel.base[j];
                float acc = 0.0f;
                #pragma unroll
                for (int c = 0; c < 5; ++c) {
                    float4 p0 = *(const float4*)&pw[base + 8 * c];
                    float4 p1 = *(const float4*)&pw[base + 8 * c + 4];
                    float4 wa = *(const float4*)&g_mel.w[c][j][0];
                    float4 wb = *(const float4*)&g_mel.w[c][j][4];
                    acc = fmaf(wa.x, p0.x, acc);
                    acc = fmaf(wa.y, p0.y, acc);
                    acc = fmaf(wa.z, p0.z, acc);
                    acc = fmaf(wa.w, p0.w, acc);
                    acc = fmaf(wb.x, p1.x, acc);
                    acc = fmaf(wb.y, p1.y, acc);
                    acc = fmaf(wb.z, p1.z, acc);
                    acc = fmaf(wb.w, p1.w, acc);
                }
                res[j * FPB + wv] = __logf(fmaxf(acc, EPSV));
            }
        }
    }
    __syncthreads();

    // ---- transposed output, 8B bursts ----
    const int nval = min(FPB, NFRM - f0);
    if (tid < NMELS) {
        size_t o = ((size_t)bb * NMELS + tid) * NFRM + (size_t)f0;
        *(float2*)&out[o] = make_float2(res[tid * 4 + 0], res[tid * 4 + 1]);
        if (nval == 4)
            *(float2*)&out[o + 2] = make_float2(res[tid * 4 + 2], res[tid * 4 + 3]);
    }
}

extern "C" void kernel_launch(void* const* d_in, const int* in_sizes, int n_in,
                              void* d_out, int out_size, void* d_ws, size_t ws_size,
                              hipStream_t stream)
{
    const float* wav = (const float*)d_in[0];
    float* out = (float*)d_out;
    fbank_kernel<<<dim3(32 * BPB), dim3(256), 0, stream>>>(wav, out);
}

// Round 11
// 37.515 us; speedup vs baseline: 1.5489x; 1.2635x over previous
//
#include <hip/hip_runtime.h>
#include <math.h>

#define NWIN   400
#define NSHIFT 160
#define NMELS  80
#define NFRM   998
#define WLEN   160000
#define FPB    8
#define BPB    125          // frame-blocks per batch (124 full + 1 tail of 6)
#define EPSV   1.1920929e-07f

// ================= compile-time table generation (no setup kernel) ==========
constexpr double KPI = 3.14159265358979323846;

constexpr double kcos(double x) {           // |x| <= 7, err < 1e-14
    double x2 = x * x, t = 1.0, s = 1.0;
    for (int k = 1; k <= 22; ++k) { t *= -x2 / (double)((2*k-1)*(2*k)); s += t; }
    return s;
}
constexpr double ksin(double x) {
    double x2 = x * x, t = x, s = x;
    for (int k = 1; k <= 22; ++k) { t *= -x2 / (double)((2*k)*(2*k+1)); s += t; }
    return s;
}
constexpr double kln(double a) {            // a > 0
    double m = a; int e = 0;
    while (m < 0.70710678118654752) { m *= 2.0; --e; }
    while (m >= 1.41421356237309505) { m *= 0.5; ++e; }
    double z = (m - 1.0) / (m + 1.0), z2 = z * z, t = z, s = 0.0;
    for (int k = 0; k <= 14; ++k) { s += t / (double)(2*k+1); t *= z2; }
    return 2.0 * s + (double)e * 0.69314718055994530942;
}
constexpr double kexp(double y) {           // |y| <= 10
    int n = (int)(y * 1.4426950408889634 + (y >= 0.0 ? 0.5 : -0.5));
    double r = y - (double)n * 0.69314718055994530942;
    double t = 1.0, s = 1.0;
    for (int k = 1; k <= 16; ++k) { t *= r / (double)k; s += t; }
    double p = 1.0;
    int an = n >= 0 ? n : -n;
    for (int i = 0; i < an; ++i) p *= (n >= 0 ? 2.0 : 0.5);
    return s * p;
}

struct alignas(16) WinT  { float v[NWIN]; };
struct alignas(16) Tw16T { float v[3][64][2]; };
struct alignas(16) TwaT  { float v[4][64][2]; };
struct alignas(16) WexpT { float v[128][2]; };
struct alignas(16) MelT  { int base[NMELS]; float w[5][NMELS][8]; };

constexpr WinT make_win() {
    WinT t{};
    for (int n = 0; n < NWIN; ++n) {
        double a = 0.5 - 0.5 * kcos(2.0 * KPI * (double)n / 399.0);
        if (a < 0.0) a = 0.0;
        t.v[n] = (a <= 0.0) ? 0.0f : (float)kexp(0.85 * kln(a));  // a^0.85
    }
    return t;
}
constexpr Tw16T make_tw16() {
    Tw16T t{};
    for (int c = 1; c <= 3; ++c)
        for (int L = 0; L < 64; ++L) {
            int a = L & 3;
            double th = -KPI * (double)(a * c) / 8.0;
            t.v[c-1][L][0] = (float)kcos(th);
            t.v[c-1][L][1] = (float)ksin(th);
        }
    return t;
}
constexpr TwaT make_twa() {
    TwaT t{};
    for (int c = 0; c < 4; ++c)
        for (int L = 0; L < 64; ++L) {
            int q = L >> 2, a = L & 3;
            int r2 = ((a & 1) << 1) | (a >> 1);
            double th = -KPI * (double)(q * (c + 4 * r2)) / 128.0;
            t.v[c][L][0] = (float)kcos(th);
            t.v[c][L][1] = (float)ksin(th);
        }
    return t;
}
constexpr WexpT make_wexp() {
    WexpT t{};
    for (int k = 0; k < 128; ++k) {
        double th = KPI * (double)k / 256.0;
        t.v[k][0] = (float)kcos(th);
        t.v[k][1] = (float)(-ksin(th));
    }
    return t;
}
constexpr MelT make_mel() {
    MelT t{};
    double ML = 1127.0 * kln(1.0 + 20.0 / 700.0);
    double MH = 1127.0 * kln(1.0 + 8000.0 / 700.0);
    double DD = (MH - ML) / 81.0;
    for (int j = 0; j < NMELS; ++j) {
        double mlo = ML + (double)j * DD;
        double flo = 700.0 * (kexp(mlo / 1127.0) - 1.0);
        int blo = (int)(flo / 31.25); if (blo < 1) blo = 1;
        int base = blo & ~7;                 // aligned; spans fit in 5 chunks
        t.base[j] = base;
        for (int c = 0; c < 5; ++c)
            for (int i = 0; i < 8; ++i) {
                int b = base + 8 * c + i;
                double w = 0.0;
                if (b >= 1 && b <= 255) {
                    double u = (1127.0 * kln(1.0 + (double)b * 31.25 / 700.0) - ML) / DD;
                    double lo = u - (double)j, hi = (double)(j + 2) - u;
                    w = lo < hi ? lo : hi;
                    if (w < 0.0) w = 0.0;    // triangle clamps outside [blo,bhi]
                }
                t.w[c][j][i] = (float)w;
            }
    }
    return t;
}

__device__ constexpr WinT  g_win  = make_win();
__device__ constexpr Tw16T g_tw16 = make_tw16();
__device__ constexpr TwaT  g_twa  = make_twa();
__device__ constexpr WexpT g_wexp = make_wexp();
__device__ constexpr MelT  g_mel  = make_mel();

// ============================================================================
// DPP quad_perm cross-lane (VALU pipe, no LDS, no address math)
#define DPPF(v, ctrl) __int_as_float(__builtin_amdgcn_mov_dpp(__float_as_int(v), ctrl, 0xF, 0xF, true))
// xor2 within quad: [2,3,0,1] = 0x4E ; xor1: [1,0,3,2] = 0xB1

// DFT-16: radix-4 over local slots (sub-idx b), W16^{ac} twiddle, radix-4
// across the quad (sub-idx a) via DPP. Input: slot b holds x[a+4b] (a=lane&3).
// Output: slot c holds Y[c + 4*rev2(a)].
__device__ __forceinline__ void dft16_quad(float zx[4], float zy[4],
    float2 w1, float2 w2, float2 w3, bool b1, bool b2, bool b3)
{
    float t0x = zx[0]+zx[2], t0y = zy[0]+zy[2];
    float t1x = zx[1]+zx[3], t1y = zy[1]+zy[3];
    float t2x = zx[0]-zx[2], t2y = zy[0]-zy[2];
    float t3x = zx[1]-zx[3], t3y = zy[1]-zy[3];
    float p0x = t0x+t1x, p0y = t0y+t1y;
    float p2x = t0x-t1x, p2y = t0y-t1y;
    float p1x = t2x+t3y, p1y = t2y-t3x;          // W4 = -i
    float p3x = t2x-t3y, p3y = t2y+t3x;
    zx[0] = p0x;                     zy[0] = p0y;
    zx[1] = p1x*w1.x - p1y*w1.y;     zy[1] = p1x*w1.y + p1y*w1.x;
    zx[2] = p2x*w2.x - p2y*w2.y;     zy[2] = p2x*w2.y + p2y*w2.x;
    zx[3] = p3x*w3.x - p3y*w3.y;     zy[3] = p3x*w3.y + p3y*w3.x;
    #pragma unroll
    for (int c = 0; c < 4; ++c) {
        float vx = zx[c], vy = zy[c];
        float ex = DPPF(vx, 0x4E), ey = DPPF(vy, 0x4E);   // partner a^2
        float ux = ex + (b2 ? -vx : vx);
        float uy = ey + (b2 ? -vy : vy);
        float rx = b3 ? uy : ux;                          // *(-i) on lane a==3
        float ry = b3 ? -ux : uy;
        float fx = DPPF(rx, 0xB1), fy = DPPF(ry, 0xB1);   // partner a^1
        zx[c] = fx + (b1 ? -rx : rx);
        zy[c] = fy + (b1 ? -ry : ry);
    }
}

// untangle pair power: X = E + W*O (and conj-partner), p = |X|^2
__device__ __forceinline__ void pairpow(float2 Zk, float2 Zm, float2 w,
                                        float& pk, float& pm)
{
    float Sx = Zk.x + Zm.x, Sy = Zk.y - Zm.y;   // 2E
    float Ox = Zk.y + Zm.y, Oy = Zm.x - Zk.x;   // 2O
    float Ux = fmaf(w.x, Ox, -w.y * Oy), Uy = fmaf(w.x, Oy, w.y * Ox);
    float q1 = Sx + Ux, q2 = Sy + Uy;
    float q3 = Sx - Ux, q4 = Sy - Uy;
    pk = 0.25f * fmaf(q1, q1, q2 * q2);
    pm = 0.25f * fmaf(q3, q3, q4 * q4);
}

__global__ __launch_bounds__(256, 8)
void fbank_kernel(const float* __restrict__ wav, float* __restrict__ out)
{
    __shared__ __align__(16) float zbf[FPB][512];   // y -> B -> X -> pw, in place
    __shared__ __align__(16) float res[NMELS * FPB];
    // LDS = 16384 + 2560 = 18944 B -> 8 blocks/CU (full 32-wave cap)

    const int tid  = threadIdx.x;
    const int lane = tid & 63;
    const int wv   = tid >> 6;
    const int bb   = blockIdx.x / BPB;
    const int f0   = (blockIdx.x % BPB) * BPB ? 0 : 0; // placeholder (replaced below)
    const int f0_  = (blockIdx.x % BPB) * FPB;
    const int sA   = wv, sB = wv + 4;
    // frame A always valid (f0_+3 <= 995 < 998); clamp frame B in tail so all
    // loads stay in-bounds; its results are computed but never emitted.
    const int fB   = min(f0_ + sB, NFRM - 1);

    float* zfA = zbf[sA];
    float* zfB = zbf[sB];

    // ---- window regs, shared by both frames ----
    float wn[7];
    #pragma unroll
    for (int t = 0; t < 7; ++t) {
        int n = 64 * t + lane;
        wn[t] = (t < 6 || lane < 16) ? g_win.v[n] : 0.0f;
    }

    // ---- preprocess both frames: de-mean, pre-emph, window; linear y ----
    #pragma unroll
    for (int fi = 0; fi < 2; ++fi) {
        const int frame = fi ? fB : (f0_ + sA);
        float* zf = fi ? zfB : zfA;
        const float* xp = wav + (size_t)bb * WLEN + (size_t)frame * NSHIFT;
        float xc[7], xm[7];
        float s = 0.0f;
        #pragma unroll
        for (int t = 0; t < 7; ++t) {
            int n = 64 * t + lane;
            bool vn = (t < 6 || lane < 16);
            xc[t] = vn ? xp[n] : 0.0f;
            xm[t] = (vn && n > 0) ? xp[n - 1] : 0.0f;   // L1-hit reload
            s += xc[t];
        }
        if (lane == 0) xm[0] = xc[0];                   // ref: prev[0] = x[0]
        #pragma unroll
        for (int off = 32; off > 0; off >>= 1) s += __shfl_xor(s, off, 64);
        const float mu3 = 0.03f * (s * (1.0f / (float)NWIN));
        #pragma unroll
        for (int t = 0; t < 7; ++t) {
            bool vn = (t < 6 || lane < 16);
            float y = vn ? (fmaf(-0.97f, xm[t], xc[t]) - mu3) * wn[t] : 0.0f;
            zf[64 * t + lane] = y;
        }
        zf[448 + lane] = 0.0f;                          // pad y[448..511]
    }

    // ---- 256-pt FFT as radix-16 x radix-16, in place, both frames ----
    const int a  = lane & 3, q = lane >> 2;
    const int r2 = ((a & 1) << 1) | (a >> 1);           // rev2(a)
    const bool b1 = (a & 1) != 0, b2 = (a & 2) != 0, b3 = (a == 3);
    {
        const float2* t16 = (const float2*)g_tw16.v;
        float2 w1 = t16[lane], w2 = t16[64 + lane], w3 = t16[128 + lane];
        const float2* twa = (const float2*)g_twa.v;
        float2 ta[4];
        #pragma unroll
        for (int c = 0; c < 4; ++c) ta[c] = twa[c * 64 + lane];

        float2* zcA = (float2*)zfA;
        float2* zcB = (float2*)zfB;
        const int ra = q + 16 * a;
        float xA[4], yA[4], xB[4], yB[4];

        // pass A: read z linear (all reads precede in-place writes; DS ops
        // are in-order per wave — same property rounds 2-10 relied on)
        #pragma unroll
        for (int b = 0; b < 4; ++b) { float2 v = zcA[ra + 64*b]; xA[b] = v.x; yA[b] = v.y; }
        #pragma unroll
        for (int b = 0; b < 4; ++b) { float2 v = zcB[ra + 64*b]; xB[b] = v.x; yB[b] = v.y; }
        dft16_quad(xA, yA, w1, w2, w3, b1, b2, b3);
        dft16_quad(xB, yB, w1, w2, w3, b1, b2, b3);
        #pragma unroll
        for (int c = 0; c < 4; ++c) {                   // twiddle + swz write
            int idx = 16*c + 64*r2 + q;
            int sw  = idx ^ ((idx >> 4) & 15);
            zcA[sw] = make_float2(xA[c]*ta[c].x - yA[c]*ta[c].y,
                                  xA[c]*ta[c].y + yA[c]*ta[c].x);
            zcB[sw] = make_float2(xB[c]*ta[c].x - yB[c]*ta[c].y,
                                  xB[c]*ta[c].y + yB[c]*ta[c].x);
        }
        // pass B: read B[n1=a+4b][k1=q] swizzled
        #pragma unroll
        for (int b = 0; b < 4; ++b) {
            int idx = 16*q + a + 4*b;
            int sw  = idx ^ ((idx >> 4) & 15);
            float2 v = zcA[sw]; xA[b] = v.x; yA[b] = v.y;
            float2 u = zcB[sw]; xB[b] = u.x; yB[b] = u.y;
        }
        dft16_quad(xA, yA, w1, w2, w3, b1, b2, b3);
        dft16_quad(xB, yB, w1, w2, w3, b1, b2, b3);
        #pragma unroll
        for (int c = 0; c < 4; ++c) {                   // X natural order
            int idx = q + 16*c + 64*r2;
            zcA[idx] = make_float2(xA[c], yA[c]);
            zcB[idx] = make_float2(xB[c], yB[c]);
        }
    }

    // ---- single-phase untangle + power, in place, both frames ----
    {
        float2* zcA = (float2*)zfA;
        float2* zcB = (float2*)zfB;
        const float2* we = (const float2*)g_wexp.v;
        float2 wk1 = we[lane], wk2 = we[64 + lane];
        const int m1 = (256 - lane) & 255;              // 0 or 193..255
        const int m2 = 192 - lane;                      // 129..192
        // ALL reads first (both frames), then writes
        float2 Ak1 = zcA[lane], Am1 = zcA[m1], Ak2 = zcA[64 + lane], Am2 = zcA[m2];
        float2 A128 = zcA[128];
        float2 Bk1 = zcB[lane], Bm1 = zcB[m1], Bk2 = zcB[64 + lane], Bm2 = zcB[m2];
        float2 B128 = zcB[128];
        float pk, pm;
        pairpow(Ak1, Am1, wk1, pk, pm);
        zfA[lane] = pk; if (m1) zfA[m1] = pm;
        pairpow(Ak2, Am2, wk2, pk, pm);
        zfA[64 + lane] = pk; zfA[m2] = pm;
        pairpow(Bk1, Bm1, wk1, pk, pm);
        zfB[lane] = pk; if (m1) zfB[m1] = pm;
        pairpow(Bk2, Bm2, wk2, pk, pm);
        zfB[64 + lane] = pk; zfB[m2] = pm;
        if (lane == 0) {
            zfA[128] = fmaf(A128.x, A128.x, A128.y * A128.y);
            zfB[128] = fmaf(B128.x, B128.x, B128.y * B128.y);
        }
        if (lane < 32) { zfA[256 + lane] = 0.0f; zfB[256 + lane] = 0.0f; }
    }

    // ---- mel gather: fixed 5 chunks, f32 weights; 160 jobs over 64 lanes ----
    {
        auto gather1 = [&](const float* pw, int j, int slot) {
            const int base = g_mel.base[j];
            float acc = 0.0f;
            #pragma unroll
            for (int c = 0; c < 5; ++c) {
                float4 p0 = *(const float4*)&pw[base + 8 * c];
                float4 p1 = *(const float4*)&pw[base + 8 * c + 4];
                float4 wa = *(const float4*)&g_mel.w[c][j][0];
                float4 wb = *(const float4*)&g_mel.w[c][j][4];
                acc = fmaf(wa.x, p0.x, acc); acc = fmaf(wa.y, p0.y, acc);
                acc = fmaf(wa.z, p0.z, acc); acc = fmaf(wa.w, p0.w, acc);
                acc = fmaf(wb.x, p1.x, acc); acc = fmaf(wb.y, p1.y, acc);
                acc = fmaf(wb.z, p1.z, acc); acc = fmaf(wb.w, p1.w, acc);
            }
            res[j * FPB + slot] = __logf(fmaxf(acc, EPSV));
        };
        gather1(zfA, lane, sA);                         // mels 0..63, frame A
        gather1(zfB, lane, sB);                         // mels 0..63, frame B
        if (lane < 32) {                                // mels 64..79, both
            int l2 = lane & 15, fb = lane >> 4;
            gather1(fb ? zfB : zfA, 64 + l2, fb ? sB : sA);
        }
    }
    __syncthreads();

    // ---- transposed output, 8B bursts ----
    const int nval = min(FPB, NFRM - f0_);              // 8, or 6 in tail
    if (tid < NMELS) {
        size_t o = ((size_t)bb * NMELS + tid) * NFRM + (size_t)f0_;
        const float* r = &res[tid * FPB];
        *(float2*)&out[o]     = make_float2(r[0], r[1]);
        *(float2*)&out[o + 2] = make_float2(r[2], r[3]);
        *(float2*)&out[o + 4] = make_float2(r[4], r[5]);
        if (nval == 8)
            *(float2*)&out[o + 6] = make_float2(r[6], r[7]);
    }
    (void)f0;
}

extern "C" void kernel_launch(void* const* d_in, const int* in_sizes, int n_in,
                              void* d_out, int out_size, void* d_ws, size_t ws_size,
                              hipStream_t stream)
{
    const float* wav = (const float*)d_in[0];
    float* out = (float*)d_out;
    fbank_kernel<<<dim3(32 * BPB), dim3(256), 0, stream>>>(wav, out);
}